// Round 2
// baseline (1220.748 us; speedup 1.0000x reference)
//
#include <hip/hip_runtime.h>

#define ORB_A 8

// ---------------------------------------------------------------------------
// Kernel A: per-orbital weighted energy e[n].
//   e[n] = sum_{ab} h1[n,a,b]*u[a]*x[b]  +  sum_{abcd} h2[n,a,b,c,d]*W[ab]*x[c]*x[d]
//   u[a] = sum_t ampl[t]*v[t,n,a];  W[a,b] = sum_t ampl[t]*v[t,n,a]*v[t,n,b]
// One wave (64 lanes) per orbital; 4 waves (4 orbitals) per 256-thread block.
// h2 sweep: float4 group k = j*64 + lane  ->  ab = j*4 + (lane>>4),
//   c = (lane>>1)&7, dhalf = lane&1  => fully coalesced 1KB/wave/instruction.
// ---------------------------------------------------------------------------
__global__ __launch_bounds__(256) void energy_kernel(
    const float* __restrict__ h1,     // [N,8,8]
    const float* __restrict__ h2,     // [N,8,8,8,8]
    const float* __restrict__ v,      // [T,N,8]
    const float* __restrict__ ampls,  // [T]
    const float* __restrict__ x,      // [N,8]
    float* __restrict__ e,            // [N] out
    int N, int T)
{
    __shared__ float Wlds[4][64];
    const int wave = threadIdx.x >> 6;
    const int lane = threadIdx.x & 63;
    int n = blockIdx.x * 4 + wave;
    const bool active = (n < N);
    if (!active) n = N - 1;  // clamp: duplicate compute, store is guarded

    const float* xn = x + (size_t)n * ORB_A;

    // ---- per-lane W entry (a = lane>>3, b = lane&7) and u[a]
    const int a = lane >> 3;
    const int b = lane & 7;
    float w  = 0.f;
    float ua = 0.f;
    for (int t = 0; t < T; ++t) {
        const float* vt = v + ((size_t)t * N + n) * ORB_A;
        const float amp = ampls[t];
        const float va  = vt[a];
        w  += amp * va * vt[b];
        ua += amp * va;
    }
    Wlds[wave][lane] = w;

    // ---- h1 contribution: one element per lane
    float acc = h1[(size_t)n * 64 + lane] * ua * xn[b];

    __syncthreads();

    // ---- per-lane coefficients for the h2 sweep
    const int   hi = lane >> 4;
    const float xc = xn[(lane >> 1) & 7];
    const float4 xd = *(const float4*)(xn + (lane & 1) * 4);
    float coeff[16];
#pragma unroll
    for (int j = 0; j < 16; ++j)
        coeff[j] = Wlds[wave][j * 4 + hi] * xc;   // broadcast LDS read, no conflicts

    // ---- main h2 sweep: 16 KB contiguous per wave, 16 x float4 per lane
    const float4* h2p = (const float4*)(h2 + (size_t)n * 4096);
#pragma unroll
    for (int j = 0; j < 16; ++j) {
        const float4 hv = h2p[j * 64 + lane];
        acc += coeff[j] * (hv.x * xd.x + hv.y * xd.y + hv.z * xd.z + hv.w * xd.w);
    }

    // ---- wave reduction
#pragma unroll
    for (int off = 32; off; off >>= 1) acc += __shfl_xor(acc, off, 64);
    if (lane == 0 && active) e[n] = acc;
}

// ---------------------------------------------------------------------------
// Kernel B: exclusive prefix sum of counts -> offs[M]. Single 256-thread block.
// ---------------------------------------------------------------------------
__global__ __launch_bounds__(256) void scan_kernel(
    const int* __restrict__ counts, int M, int* __restrict__ offs)
{
    __shared__ int partial[256];
    const int tid = threadIdx.x;
    const int chunk = (M + 255) / 256;
    const int start = tid * chunk;
    const int end   = min(start + chunk, M);

    int s = 0;
    for (int i = start; i < end; ++i) s += counts[i];
    partial[tid] = s;
    __syncthreads();

    // Hillis-Steele inclusive scan over 256 partials
    for (int off = 1; off < 256; off <<= 1) {
        const int self = partial[tid];
        const int prev = (tid >= off) ? partial[tid - off] : 0;
        __syncthreads();
        partial[tid] = self + prev;
        __syncthreads();
    }

    int run = (tid > 0) ? partial[tid - 1] : 0;  // exclusive base of this chunk
    for (int i = start; i < end; ++i) { offs[i] = run; run += counts[i]; }
}

// ---------------------------------------------------------------------------
// Kernel C: segment sum per molecule, divide by sum(ampls). One wave / molecule.
// ---------------------------------------------------------------------------
__global__ __launch_bounds__(64) void reduce_kernel(
    const float* __restrict__ e, const int* __restrict__ offs,
    const int* __restrict__ counts, const float* __restrict__ ampls,
    int T, float* __restrict__ out)
{
    const int m = blockIdx.x;
    const int lane = threadIdx.x;
    const int start = offs[m];
    const int cnt   = counts[m];

    float acc = 0.f;
    for (int i = lane; i < cnt; i += 64) acc += e[start + i];
#pragma unroll
    for (int off = 32; off; off >>= 1) acc += __shfl_xor(acc, off, 64);

    if (lane == 0) {
        float denom = 0.f;
        for (int t = 0; t < T; ++t) denom += ampls[t];
        out[m] = acc / denom;
    }
}

// ---------------------------------------------------------------------------
extern "C" void kernel_launch(void* const* d_in, const int* in_sizes, int n_in,
                              void* d_out, int out_size, void* d_ws, size_t ws_size,
                              hipStream_t stream) {
    const float* h1     = (const float*)d_in[0];
    const float* h2     = (const float*)d_in[1];
    const float* v      = (const float*)d_in[2];
    const float* ampls  = (const float*)d_in[3];
    const float* x      = (const float*)d_in[4];
    const int*   counts = (const int*)d_in[5];
    float* out = (float*)d_out;

    const int T = in_sizes[3];
    const int N = in_sizes[4] / ORB_A;   // x_i is [N, A]
    const int M = in_sizes[5];

    float* e   = (float*)d_ws;           // N floats
    int*  offs = (int*)((float*)d_ws + N);  // M ints

    energy_kernel<<<(N + 3) / 4, 256, 0, stream>>>(h1, h2, v, ampls, x, e, N, T);
    scan_kernel<<<1, 256, 0, stream>>>(counts, M, offs);
    reduce_kernel<<<M, 64, 0, stream>>>(e, offs, counts, ampls, T, out);
}